// Round 5
// baseline (108.339 us; speedup 1.0000x reference)
//
#include <hip/hip_runtime.h>
#include <hip/hip_bf16.h>
#include <float.h>
#include <math.h>

#define CDIM 128

typedef __attribute__((ext_vector_type(8))) short short8v;   // 8 bf16 = 1 MFMA A/B frag
typedef __attribute__((ext_vector_type(4))) short short4v;   // 4 bf16 (8B LDS store)
typedef __attribute__((ext_vector_type(4))) float f32x4;     // MFMA C/D frag

__device__ __forceinline__ short bf16b(float f) {
    __hip_bfloat16 h = __float2bfloat16(f);
    return __builtin_bit_cast(short, h);
}

// fast tanh via hardware exp: tanh(y) = 1 - 2/(exp(2y)+1)
__device__ __forceinline__ float tanh_fast(float y) {
    float e = __expf(2.0f * y);
    return 1.0f - 2.0f / (e + 1.0f);
}

__device__ __forceinline__ int lower_bound_i(const int* __restrict__ b, int n, int v) {
    int lo = 0, hi = n;
    while (lo < hi) { int mid = (lo + hi) >> 1; if (b[mid] < v) lo = mid + 1; else hi = mid; }
    return lo;
}

__global__ void seg_bounds_kernel(const int* __restrict__ batch, int N, int G,
                                  int* __restrict__ seg) {
    int g = blockIdx.x * blockDim.x + threadIdx.x;
    if (g < G) seg[g] = lower_bound_i(batch, N, g);
    if (g == 0) seg[G] = N;
}

// Pre-pack proj_w into bf16 MFMA B-fragments.
// Frag f = ct*4+ks, lane l: col c = ct*16+(l&15), k = ks*32+(l>>4)*8+j  (j=0..7)
__global__ void wconv_kernel(const float* __restrict__ proj_w, short* __restrict__ wfrag) {
    int tid = blockIdx.x * 256 + threadIdx.x;       // 0..2047
    int f = tid >> 6, l = tid & 63;
    int c  = ((f >> 2) << 4) | (l & 15);
    int k0 = ((f & 3) << 5) | ((l >> 4) << 3);
    short8v v;
    #pragma unroll
    for (int j = 0; j < 8; ++j) v[j] = bf16b(proj_w[c * CDIM + k0 + j]);
    ((short8v*)wfrag)[tid] = v;
}

// One block (256 thr = 4 waves) per graph. Wave w owns column-tiles {2w, 2w+1}.
// Two-deep software pipeline: chunk k+1's global loads are issued right after
// chunk k's LDS-stage barrier, hiding HBM latency under MFMA+epilogue+softmax.
// fp32 x stays in registers for exact pooling; bf16 copy goes to swizzled LDS
// once for the MFMA A side. x read from HBM exactly once. 3 barriers/chunk.
__launch_bounds__(256, 3)
__global__ void pool_kernel(const float* __restrict__ x,
                            const short* __restrict__ wfrag,
                            const float* __restrict__ proj_b,
                            const float* __restrict__ score_w,
                            const float* __restrict__ score_b,
                            const int* __restrict__ seg,
                            float* __restrict__ out,
                            int N) {
    // LDS: 16KB XsB + 1KB ps + 256B cs + 4KB red + bc = ~21.3KB
    __shared__ short XsB[64 * 128];           // bf16, short idx: row*128 + (k ^ ((row&7)<<3))
    __shared__ float ps[4 * 64];              // per-wave score partials
    __shared__ float cs[64];                  // chunk scores -> exp weights
    __shared__ __align__(16) float red[8 * 128];
    __shared__ float bc[2];                   // {scale, chunk exp-sum}

    const int g = blockIdx.x;
    const int t = threadIdx.x;
    const int lane = t & 63;
    const int w = t >> 6;                     // wave id: owns col-tiles 2w, 2w+1
    const int start = seg[g];
    const int cnt = seg[g + 1] - start;

    if (cnt <= 0) {                           // empty graph pools to zeros
        if (t < CDIM) out[g * CDIM + t] = 0.0f;
        return;
    }

    const float4* __restrict__ x4 = (const float4*)x;
    const int g8 = t >> 5;                    // stage/pool row phase (0..7)
    const int c4 = t & 31;                    // float4 column slot
    const int al = lane & 15, ah = lane >> 4;

    // ---- prologue: issue chunk 0 loads FIRST (deepest latency) ----
    float4 xr[8], xn[8];
    #pragma unroll
    for (int i = 0; i < 8; ++i) {
        int row = g8 + (i << 3);
        size_t gr = (size_t)min(start + row, N - 1);
        xr[i] = x4[gr * 32 + c4];
    }

    // W fragments for this wave's 2 column-tiles: 8 frags = 32 VGPR (L2-hot)
    short8v wf[2][4];
    {
        const short8v* wfg = (const short8v*)wfrag;
        #pragma unroll
        for (int j = 0; j < 2; ++j)
            #pragma unroll
            for (int ks = 0; ks < 4; ++ks)
                wf[j][ks] = wfg[((((w << 1) | j) << 2 | ks) << 6) | lane];
    }
    float swl[2], pbl[2];
    #pragma unroll
    for (int j = 0; j < 2; ++j) {
        swl[j] = score_w[(((w << 1) | j) << 4) + al];
        pbl[j] = proj_b[(((w << 1) | j) << 4) + al];
    }
    const float sb = score_b[0];

    float m_run = -FLT_MAX, l_run = 0.0f;
    float4 pa = make_float4(0.f, 0.f, 0.f, 0.f);

    for (int cb = 0; cb < cnt; cb += 64) {
        const int chunk_n = min(64, cnt - cb);

        // ---- stage: fp32 regs -> bf16 swizzled LDS (converted ONCE) ----
        #pragma unroll
        for (int i = 0; i < 8; ++i) {
            int row = g8 + (i << 3);
            short4v b;
            b[0] = bf16b(xr[i].x); b[1] = bf16b(xr[i].y);
            b[2] = bf16b(xr[i].z); b[3] = bf16b(xr[i].w);
            *(short4v*)&XsB[(row << 7) | ((c4 << 2) ^ ((row & 7) << 3))] = b;
        }
        __syncthreads();                      // sync1: XsB ready

        // ---- prefetch chunk k+1 into xn (hidden under MFMA+softmax) ----
        const bool pf = (cb + 64 < cnt);
        if (pf) {
            #pragma unroll
            for (int i = 0; i < 8; ++i) {
                int row = g8 + (i << 3);
                size_t gr = (size_t)min(start + cb + 64 + row, N - 1);
                xn[i] = x4[gr * 32 + c4];
            }
        }

        // ---- per row-tile: 8 MFMA + tanh/score epilogue (acc live = 8 VGPR) ----
        #pragma unroll
        for (int rt = 0; rt < 4; ++rt) {
            const int arow = (rt << 4) | al;
            const int rsw = (arow & 7) << 3;
            f32x4 a0 = (f32x4){0.f, 0.f, 0.f, 0.f};
            f32x4 a1 = (f32x4){0.f, 0.f, 0.f, 0.f};
            #pragma unroll
            for (int ks = 0; ks < 4; ++ks) {
                short8v af = *(const short8v*)&XsB[(arow << 7) | (((ks << 5) | (ah << 3)) ^ rsw)];
                a0 = __builtin_amdgcn_mfma_f32_16x16x32_bf16(af, wf[0][ks], a0, 0, 0, 0);
                a1 = __builtin_amdgcn_mfma_f32_16x16x32_bf16(af, wf[1][ks], a1, 0, 0, 0);
            }
            #pragma unroll
            for (int r = 0; r < 4; ++r) {
                float s = swl[0] * tanh_fast(a0[r] + pbl[0])
                        + swl[1] * tanh_fast(a1[r] + pbl[1]);
                s += __shfl_xor(s, 1); s += __shfl_xor(s, 2);
                s += __shfl_xor(s, 4); s += __shfl_xor(s, 8);
                if (al == 0) ps[(w << 6) | (rt << 4) | (ah << 2) | r] = s;
            }
        }
        __syncthreads();                      // sync2: ps complete, XsB reads done

        // ---- online softmax update (wave 0) ----
        if (t < 64) {
            float v = (t < chunk_n)
                    ? (ps[t] + ps[64 + t] + ps[128 + t] + ps[192 + t] + sb)
                    : -FLT_MAX;
            float mx = v;
            mx = fmaxf(mx, __shfl_xor(mx, 1));  mx = fmaxf(mx, __shfl_xor(mx, 2));
            mx = fmaxf(mx, __shfl_xor(mx, 4));  mx = fmaxf(mx, __shfl_xor(mx, 8));
            mx = fmaxf(mx, __shfl_xor(mx, 16)); mx = fmaxf(mx, __shfl_xor(mx, 32));
            float m_new = fmaxf(m_run, mx);
            float sc = __expf(m_run - m_new);           // first chunk: exp(-huge)=0
            float e = (t < chunk_n) ? __expf(v - m_new) : 0.f;
            float ssum = e;
            ssum += __shfl_xor(ssum, 1);  ssum += __shfl_xor(ssum, 2);
            ssum += __shfl_xor(ssum, 4);  ssum += __shfl_xor(ssum, 8);
            ssum += __shfl_xor(ssum, 16); ssum += __shfl_xor(ssum, 32);
            cs[t] = e;
            if (t == 0) { bc[0] = sc; bc[1] = ssum; }
            m_run = m_new;
        }
        __syncthreads();                      // sync3: cs/bc ready

        // ---- rescale + pooling accumulate (registers + cs broadcast) ----
        const float sc = bc[0];
        l_run = l_run * sc + bc[1];
        pa.x *= sc; pa.y *= sc; pa.z *= sc; pa.w *= sc;
        #pragma unroll
        for (int i = 0; i < 8; ++i) {
            float e = cs[g8 + (i << 3)];              // 0 for pad rows; broadcast read
            pa.x += e * xr[i].x; pa.y += e * xr[i].y;
            pa.z += e * xr[i].z; pa.w += e * xr[i].w;
        }

        // ---- rotate pipeline registers ----
        if (pf) {
            #pragma unroll
            for (int i = 0; i < 8; ++i) xr[i] = xn[i];
        }
    }

    // ---- cross-group reduce + normalize ----
    *(float4*)&red[(g8 << 7) + (c4 << 2)] = pa;
    __syncthreads();
    if (t < CDIM) {
        float v = 0.f;
        #pragma unroll
        for (int j = 0; j < 8; ++j) v += red[j * CDIM + t];
        out[g * CDIM + t] = v * (1.0f / fmaxf(l_run, 1e-30f));
    }
}

extern "C" void kernel_launch(void* const* d_in, const int* in_sizes, int n_in,
                              void* d_out, int out_size, void* d_ws, size_t ws_size,
                              hipStream_t stream) {
    const float* x       = (const float*)d_in[0];
    const float* proj_w  = (const float*)d_in[1];
    const float* proj_b  = (const float*)d_in[2];
    const float* score_w = (const float*)d_in[3];
    const float* score_b = (const float*)d_in[4];
    const int*   batch   = (const int*)d_in[5];

    const int N = in_sizes[0] / CDIM;
    const int G = out_size / CDIM;

    int*   seg   = (int*)d_ws;
    short* wfrag = (short*)((char*)d_ws + (((size_t)(G + 1) * 4 + 255) & ~(size_t)255));

    seg_bounds_kernel<<<(G + 255) / 256, 256, 0, stream>>>(batch, N, G, seg);
    wconv_kernel<<<8, 256, 0, stream>>>(proj_w, wfrag);
    pool_kernel<<<G, 256, 0, stream>>>(x, wfrag, proj_b, score_w, score_b,
                                       seg, (float*)d_out, N);
}